// Round 9
// baseline (2611.988 us; speedup 1.0000x reference)
//
#include <hip/hip_runtime.h>

#define HH 1024
#define WW 1024
#define HW 1048576   // 1024*1024
#define NBLK 22      // fft blocks per dim: range(0,1024,48)

// ---------------------------------------------------------------------------
// Agent-scope RELAXED dword access — the ONLY cross-block primitives used.
// Proven R3/R4/R8: cross-XCD coherent via MALL, no cache-maintenance storm.
// R6/R7 lesson: hand-rolled sc-bit wide stores are NOT visible to these
// readers. Coalescing comes from ADDRESSING (lane-consecutive dwords).
// ---------------------------------------------------------------------------
__device__ __forceinline__ float aload(const float* p)
{
    return __uint_as_float(__hip_atomic_load((const unsigned int*)p,
                           __ATOMIC_RELAXED, __HIP_MEMORY_SCOPE_AGENT));
}
__device__ __forceinline__ void astore(float* p, float v)
{
    __hip_atomic_store((unsigned int*)p, __float_as_uint(v),
                       __ATOMIC_RELAXED, __HIP_MEMORY_SCOPE_AGENT);
}

// ---------------------------------------------------------------------------
// Kernel 1: cv, ch edge-stopping coefficients (also final outputs 1,2)
// ---------------------------------------------------------------------------
__global__ __launch_bounds__(256) void coeff_kernel(
    const float* __restrict__ guide, const float* __restrict__ img,
    float* __restrict__ cv, float* __restrict__ ch)
{
    int x = blockIdx.x * 256 + threadIdx.x;
    int y = blockIdx.y;
    int b = blockIdx.z;
    const float* g0 = guide + (size_t)b * 3 * HW;
    const float* im = img + (size_t)b * HW;
    int p = y * WW + x;
    float f0 = g0[p], f1 = g0[HW + p], f2 = g0[2 * HW + p], f3 = im[p];
    const float KK = 0.03f * 0.03f;
    if (y < HH - 1) {
        int q = p + WW;
        float s = fabsf(g0[q] - f0) + fabsf(g0[HW + q] - f1)
                + fabsf(g0[2 * HW + q] - f2) + fabsf(im[q] - f3);
        float t = s * 0.25f;
        cv[(size_t)b * 1023 * 1024 + p] = 1.0f / (1.0f + t * t / KK);
    }
    if (x < WW - 1) {
        int q = p + 1;
        float s = fabsf(g0[q] - f0) + fabsf(g0[HW + q] - f1)
                + fabsf(g0[2 * HW + q] - f2) + fabsf(im[q] - f3);
        float t = s * 0.25f;
        ch[(size_t)b * 1024 * 1023 + y * 1023 + x] = 1.0f / (1.0f + t * t / KK);
    }
}

__device__ __forceinline__ float block_reduce(float v, float* tmp)
{
    #pragma unroll
    for (int off = 32; off > 0; off >>= 1) v += __shfl_down(v, off);
    __syncthreads();
    if ((threadIdx.x & 63) == 0) tmp[threadIdx.x >> 6] = v;
    __syncthreads();
    return tmp[0] + tmp[1] + tmp[2] + tmp[3];
}

// ---------------------------------------------------------------------------
// Kernel 2: per-(block,batch) stats: cv mean, ch mean, uniform fraction
// ---------------------------------------------------------------------------
__global__ __launch_bounds__(256) void stats_kernel(
    const float* __restrict__ cv, const float* __restrict__ ch,
    float* __restrict__ cvmA, float* __restrict__ chmA, float* __restrict__ unifA)
{
    int iy = blockIdx.x, ix = blockIdx.y, b = blockIdx.z;
    int y0 = iy * 48, x0 = ix * 48;
    int ye = min(y0 + 64, HH), xe = min(x0 + 64, WW);
    int bh = ye - y0, bw = xe - x0;
    const float* cvb = cv + (size_t)b * 1023 * 1024;
    const float* chb = ch + (size_t)b * 1024 * 1023;
    int tid = threadIdx.x;

    int cnt_cv = (bh - 1) * bw;
    float s_cv = 0.f;
    for (int k = tid; k < cnt_cv; k += 256) {
        int r = k / bw, c = k - r * bw;
        s_cv += cvb[(y0 + r) * 1024 + x0 + c];
    }
    int cnt_ch = bh * (bw - 1);
    float s_ch = 0.f;
    for (int k = tid; k < cnt_ch; k += 256) {
        int r = k / (bw - 1), c = k - r * (bw - 1);
        s_ch += chb[(y0 + r) * 1023 + x0 + c];
    }
    int uh = min(ye, 1023) - y0, uw = min(xe, 1023) - x0;
    int cnt_u = uh * uw;
    float s_u = 0.f;
    for (int k = tid; k < cnt_u; k += 256) {
        int r = k / uw, c = k - r * uw;
        int py = y0 + r, px = x0 + c;
        float a1 = 0.f, a2 = 0.f;
        #pragma unroll
        for (int dy = -1; dy <= 1; ++dy)
            #pragma unroll
            for (int dx = -1; dx <= 1; ++dx) {
                int yy = py + dy, xx = px + dx;
                if (yy >= 0 && yy < 1023 && xx >= 0 && xx < 1024) {
                    float v = cvb[yy * 1024 + xx]; a1 += v; a2 += v * v;
                }
            }
        float va = a2 * (1.f / 9.f) - (a1 * (1.f / 9.f)) * (a1 * (1.f / 9.f));
        float b1 = 0.f, b2 = 0.f;
        #pragma unroll
        for (int dy = -1; dy <= 1; ++dy)
            #pragma unroll
            for (int dx = -1; dx <= 1; ++dx) {
                int yy = py + dy, xx = px + dx;
                if (yy >= 0 && yy < 1024 && xx >= 0 && xx < 1023) {
                    float v = chb[yy * 1023 + xx]; b1 += v; b2 += v * v;
                }
            }
        float vb = b2 * (1.f / 9.f) - (b1 * (1.f / 9.f)) * (b1 * (1.f / 9.f));
        s_u += (va < 0.1f && vb < 0.1f) ? 1.f : 0.f;
    }

    __shared__ float tmp[4];
    float t_cv = block_reduce(s_cv, tmp);
    float t_ch = block_reduce(s_ch, tmp);
    float t_u  = block_reduce(s_u, tmp);
    if (tid == 0) {
        int bi = (b * NBLK + iy) * NBLK + ix;
        cvmA[bi]  = t_cv / (float)cnt_cv;
        chmA[bi]  = t_ch / (float)cnt_ch;
        unifA[bi] = t_u / (float)cnt_u;
    }
}

// ---------------------------------------------------------------------------
// Kernel 3a (fallback): one diagonal per launch, plain L2 path.
// ---------------------------------------------------------------------------
__global__ __launch_bounds__(256) void fftblk_kernel(
    float* __restrict__ depth,
    const float* __restrict__ cvmA, const float* __restrict__ chmA,
    const float* __restrict__ unifA, int d, int iy_lo)
{
    int iy = iy_lo + (int)blockIdx.x;
    int ix = d - 2 * iy;
    int b = blockIdx.y;
    int bi = (b * NBLK + iy) * NBLK + ix;
    if (!(unifA[bi] > 0.7f)) return;

    int y0 = iy * 48, x0 = ix * 48;
    int bh = min(64, HH - y0), bw = min(64, WW - x0);
    int npix = bh * bw;
    int bwm = bw - 1, bhm = bh - 1;
    int lw = (bw == 64) ? 6 : 4;
    float av = 0.24f * cvmA[bi];
    float ah = 0.24f * chmA[bi];

    __shared__ float bufA[4096], bufB[4096], bufO[4096];
    float* cur = bufA;
    float* nxt = bufB;
    int tid = threadIdx.x;
    float* gbase = depth + (size_t)b * HW + y0 * WW + x0;

    for (int idx = tid; idx < npix; idx += 256) {
        int i = idx >> lw, j = idx & bwm;
        float v = gbase[i * WW + j];
        cur[idx] = v; bufO[idx] = v;
    }
    __syncthreads();

    for (int it = 0; it < 10; ++it) {
        for (int idx = tid; idx < npix; idx += 256) {
            int i = idx >> lw, j = idx & bwm;
            float c  = cur[idx];
            float up = cur[(((i - 1) & bhm) << lw) | j];
            float dn = cur[(((i + 1) & bhm) << lw) | j];
            float lf = cur[(i << lw) | ((j - 1) & bwm)];
            float rt = cur[(i << lw) | ((j + 1) & bwm)];
            nxt[idx] = c + av * (up + dn - 2.f * c) + ah * (lf + rt - 2.f * c);
        }
        __syncthreads();
        float* t = cur; cur = nxt; nxt = t;
    }

    const float inv16 = 1.f / 16.f;
    for (int idx = tid; idx < npix; idx += 256) {
        int i = idx >> lw, j = idx & bwm;
        float wy = (y0 > 0 && i < 16) ? (float)i * inv16 : 1.f;
        float wx = (x0 > 0 && j < 16) ? (float)j * inv16 : 1.f;
        float w = wy * wx;
        gbase[i * WW + j] = bufO[idx] * (1.f - w) + cur[idx] * w;
    }
}

// ---------------------------------------------------------------------------
// Kernel 3b: GROUPED fftblk, REGISTER-TILED Jacobi (R9 rewrite).
// Wavefront deps enforced by MALL tag polling (protocol unchanged from R8).
// Inner loop: each thread owns a RHxRW cell tile in REGISTERS (16x16 threads;
// RH=bh/16, RW=bw/16 in {1,4}); per step only tile edge rows/cols go through
// LDS (parity-double-buffered -> ONE barrier/step), interior is pure VALU.
// ~3x fewer LDS ops than the bufA/B version => per-block ~3-4us instead of
// ~10us => the 43-diagonal critical path drops proportionally. LDS = 32KB
// (was 48KB) => >=4 blocks/CU => the whole 484-block wavefront fits ONE
// launch (no inter-group drain). All register indices are compile-time
// (unrolled loops + runtime guards) - no scratch spill (rule: no runtime
// indexing of register arrays).
// ---------------------------------------------------------------------------
__global__ __launch_bounds__(256) void fftblk_group(
    float* __restrict__ depth,
    const float* __restrict__ cvmA, const float* __restrict__ chmA,
    const float* __restrict__ unifA, unsigned int* __restrict__ ftags,
    int base)
{
    // decode diagonal-major index -> (iy, ix)
    int rem = base + (int)blockIdx.x;
    int iy = 0, ix = 0;
    for (int d = 0; d < 64; ++d) {
        int lo = (d > 21) ? ((d - 20) >> 1) : 0;
        int hi = ((d >> 1) < 21) ? (d >> 1) : 21;
        int wd = hi - lo + 1;
        if (rem < wd) { iy = lo + rem; ix = d - 2 * iy; break; }
        rem -= wd;
    }
    int b = blockIdx.y;
    int bi = (b * NBLK + iy) * NBLK + ix;
    int tid = threadIdx.x;

    // wait for predecessors (tags, lanes 0..3 of wave 0)
    {
        bool act = false; int di = 0, dj = 0;
        if (tid == 0) { act = (ix > 0);            di = iy;     dj = ix - 1; }
        if (tid == 1) { act = (iy > 0 && ix > 0);  di = iy - 1; dj = ix - 1; }
        if (tid == 2) { act = (iy > 0);            di = iy - 1; dj = ix;     }
        if (tid == 3) { act = (iy > 0 && ix < 21); di = iy - 1; dj = ix + 1; }
        if (tid < 4 && act) {
            const unsigned int* tp = ftags + (((b * NBLK + di) * NBLK + dj) << 4);
            int guard = 0;
            while (__hip_atomic_load(tp, __ATOMIC_RELAXED,
                                     __HIP_MEMORY_SCOPE_AGENT) < 1u) {
                if (++guard > (1 << 20)) break;
                __builtin_amdgcn_s_sleep(2);
            }
        }
    }
    __syncthreads();

    bool active = (unifA[bi] > 0.7f);
    if (active) {
        int y0 = iy * 48, x0 = ix * 48;
        int bh = min(64, HH - y0), bw = min(64, WW - x0);
        const int RH = bh >> 4;   // 4 or 1
        const int RW = bw >> 4;   // 4 or 1
        float av = 0.24f * cvmA[bi];
        float ah = 0.24f * chmA[bi];

        // edge-exchange LDS, parity-double-buffered: 4 x 2x16x64 x 4B = 32KB
        __shared__ float rT[2][16][64];   // each thread-row's TOP cells
        __shared__ float rB[2][16][64];   // each thread-row's BOTTOM cells
        __shared__ float cL[2][16][64];   // each thread-col's LEFT cells
        __shared__ float cR[2][16][64];   // each thread-col's RIGHT cells

        const int ty = tid >> 4, tx = tid & 15;
        float* gbase = depth + (size_t)b * HW + y0 * WW + x0;

        // tile into registers (orig kept for the blend)
        float cur[4][4], orig[4][4];
        #pragma unroll
        for (int r = 0; r < 4; ++r)
            #pragma unroll
            for (int c = 0; c < 4; ++c)
                if (r < RH && c < RW) {
                    float v = aload(gbase + (RH * ty + r) * WW + RW * tx + c);
                    cur[r][c] = v; orig[r][c] = v;
                }

        for (int it = 0; it < 10; ++it) {
            const int p = it & 1;
            // publish tile edges (static register indices via RH/RW branch)
            #pragma unroll
            for (int c = 0; c < 4; ++c)
                if (c < RW) {
                    rT[p][ty][RW * tx + c] = cur[0][c];
                    rB[p][ty][RW * tx + c] = (RH == 4) ? cur[3][c] : cur[0][c];
                }
            #pragma unroll
            for (int r = 0; r < 4; ++r)
                if (r < RH) {
                    cL[p][tx][RH * ty + r] = cur[r][0];
                    cR[p][tx][RH * ty + r] = (RW == 4) ? cur[r][3] : cur[r][0];
                }
            __syncthreads();

            // 5-point periodic Jacobi step, interior in registers
            float nxt[4][4];
            #pragma unroll
            for (int r = 0; r < 4; ++r)
                #pragma unroll
                for (int c = 0; c < 4; ++c)
                    if (r < RH && c < RW) {
                        float ce = cur[r][c];
                        float up = (r > 0) ? cur[r - 1][c]
                                           : rB[p][(ty - 1) & 15][RW * tx + c];
                        float dn = rT[p][(ty + 1) & 15][RW * tx + c];
                        if (r + 1 < 4) { if (r + 1 < RH) dn = cur[r + 1][c]; }
                        float lf = (c > 0) ? cur[r][c - 1]
                                           : cR[p][(tx - 1) & 15][RH * ty + r];
                        float rt = cL[p][(tx + 1) & 15][RH * ty + r];
                        if (c + 1 < 4) { if (c + 1 < RW) rt = cur[r][c + 1]; }
                        nxt[r][c] = ce + av * (up + dn - 2.f * ce)
                                       + ah * (lf + rt - 2.f * ce);
                    }
            #pragma unroll
            for (int r = 0; r < 4; ++r)
                #pragma unroll
                for (int c = 0; c < 4; ++c)
                    if (r < RH && c < RW) cur[r][c] = nxt[r][c];
            // no trailing barrier: next step writes parity p^1; the single
            // barrier above orders write(p^1) against all reads of (p^1).
        }

        // blend with original and write back (coalesced agent-scope)
        const float inv16 = 1.f / 16.f;
        #pragma unroll
        for (int r = 0; r < 4; ++r)
            #pragma unroll
            for (int c = 0; c < 4; ++c)
                if (r < RH && c < RW) {
                    int i = RH * ty + r, j = RW * tx + c;
                    float wy = (y0 > 0 && i < 16) ? (float)i * inv16 : 1.f;
                    float wx = (x0 > 0 && j < 16) ? (float)j * inv16 : 1.f;
                    float w = wy * wx;
                    astore(gbase + i * WW + j,
                           orig[r][c] * (1.f - w) + cur[r][c] * w);
                }
        asm volatile("s_waitcnt vmcnt(0)" ::: "memory");
    }
    __syncthreads();   // all waves drained before tag raise
    if (tid == 0)
        __hip_atomic_store(ftags + (bi << 4), 1u, __ATOMIC_RELAXED,
                           __HIP_MEMORY_SCOPE_AGENT);
}

// ---------------------------------------------------------------------------
// Kernel 4a (fallback, known-good): one scan iteration per launch.
// ---------------------------------------------------------------------------
__global__ __launch_bounds__(256, 4) void iter_kernel(
    const float* __restrict__ Iin, float* __restrict__ Iout,
    const float* __restrict__ cv, const float* __restrict__ ch,
    const float* __restrict__ source, const float* __restrict__ mask)
{
    const int w = blockIdx.x;
    const int xcd = w & 7, j = w >> 3;
    const int grb = xcd * 32 + (j >> 2);
    const int b  = grb >> 7;
    const int r0 = (grb & 127) * 8;
    const int c0 = (j & 3) * 256;
    const int tid = threadIdx.x;
    __shared__ float sI[10][258];
    const float* Ib  = Iin + (size_t)b * HW;
    const float* cvb = cv + (size_t)b * 1023 * 1024;
    const float* chb = ch + (size_t)b * 1024 * 1023;

    for (int k = tid; k < 10 * 258; k += 256) {
        int r = k / 258, c = k - r * 258;
        int gy = r0 - 1 + r, gx = c0 - 1 + c;
        float v = 0.f;
        if (gy >= 0 && gy < HH && gx >= 0 && gx < WW) v = Ib[gy * WW + gx];
        sI[r][c] = v;
    }

    const int gx = c0 + tid;
    float cvv[9];
    #pragma unroll
    for (int k = 0; k < 9; ++k) {
        int gr = r0 - 1 + k;
        cvv[k] = (gr >= 0 && gr < 1023) ? cvb[gr * 1024 + gx] : 0.f;
    }
    float chl[8], chh[8];
    #pragma unroll
    for (int k = 0; k < 8; ++k) {
        int rr = r0 + k;
        chh[k] = (gx < 1023) ? chb[rr * 1023 + gx] : 0.f;
        chl[k] = (gx > 0)    ? chb[rr * 1023 + gx - 1] : 0.f;
    }
    __syncthreads();

    float o[8];
    #pragma unroll
    for (int r = 0; r < 8; ++r) {
        float c  = sI[r + 1][tid + 1];
        float up = sI[r][tid + 1], dn = sI[r + 2][tid + 1];
        float lf = sI[r + 1][tid], rt = sI[r + 1][tid + 2];
        o[r] = c + 0.24f * ( cvv[r + 1] * (dn - c) - cvv[r] * (c - up)
                           + chh[r] * (rt - c)     - chl[r] * (c - lf) );
    }

    float colsum = 0.f;
    #pragma unroll
    for (int r = 0; r < 8; ++r) colsum += o[r];
    colsum += __shfl_xor(colsum, 1);
    colsum += __shfl_xor(colsum, 2);
    colsum += __shfl_xor(colsum, 4);
    float mean = colsum * (1.0f / 64.0f);

    int sy = r0 >> 3;
    int sx = (c0 >> 3) + (tid >> 3);
    int sidx = b * 128 * 128 + sy * 128 + sx;
    float ratio = (mask[sidx] < 0.5f) ? 1.0f : source[sidx] / (mean + 1e-8f);

    float* Ob = Iout + (size_t)b * HW;
    #pragma unroll
    for (int r = 0; r < 8; ++r)
        Ob[(r0 + r) * WW + c0 + tid] = o[r] * ratio;
}

// ---------------------------------------------------------------------------
// Kernel 4b: ALL 500 iterations, strip-persistent (R8, proven: 1086us,
// WRITE_SIZE == logical). Unchanged this round.
// ---------------------------------------------------------------------------
__global__ __launch_bounds__(256, 1) void iter500_strip(
    float* __restrict__ depth,
    const float* __restrict__ cv, const float* __restrict__ ch,
    const float* __restrict__ source, const float* __restrict__ mask,
    float* __restrict__ rowbuf,        // [slot2][strip256][which2][w4][c4][l64]
    unsigned int* __restrict__ tags,   // [strip256][wave4] stride-16 uints
    int niter)
{
    const int s   = blockIdx.x;        // strip 0..255
    const int b   = s >> 7;
    const int rb  = s & 127;
    const int r0  = rb * 8;
    const int tid = threadIdx.x;
    const int w   = tid >> 6;          // wave 0..3 (col segment)
    const int l   = tid & 63;
    const int gx0 = (w << 8) + (l << 2);   // first of 4 owned columns
    const int swz = (w << 8) + l;          // swizzled base: + (c<<6) per col

    __shared__ float sE[2][3][2][8];   // [slot][boundary][left/right][row]

    float* gdep = depth + (size_t)b * HW;

    // ---- field into registers (float4 rows), publish(0) ASAP ----
    float o[8][4];
    #pragma unroll
    for (int r = 0; r < 8; ++r) {
        float4 v = *(const float4*)(gdep + (size_t)(r0 + r) * WW + gx0);
        o[r][0] = v.x; o[r][1] = v.y; o[r][2] = v.z; o[r][3] = v.w;
    }
    unsigned int* mytag = tags + ((s * 4 + w) << 4);
    {
        float* dT = rowbuf + ((size_t)s * 2 + 0) * 1024 + swz;   // slot 0
        float* dB = rowbuf + ((size_t)s * 2 + 1) * 1024 + swz;
        #pragma unroll
        for (int c = 0; c < 4; ++c) { astore(dT + (c << 6), o[0][c]);
                                      astore(dB + (c << 6), o[7][c]); }
        asm volatile("s_waitcnt vmcnt(0)" ::: "memory");
        if (l == 0)
            __hip_atomic_store(mytag, 1u, __ATOMIC_RELAXED, __HIP_MEMORY_SCOPE_AGENT);
    }

    // ---- loop-invariant coefficients into registers ----
    const float* cvb = cv + (size_t)b * 1023 * 1024;
    const float* chb = ch + (size_t)b * 1024 * 1023;
    float cvv[9][4];
    #pragma unroll
    for (int k = 0; k < 9; ++k) {
        int gr = r0 - 1 + k;
        #pragma unroll
        for (int c = 0; c < 4; ++c)
            cvv[k][c] = (gr >= 0 && gr < 1023) ? cvb[(size_t)gr * 1024 + gx0 + c] : 0.f;
    }
    float chh[8][4], chl0[8];
    #pragma unroll
    for (int k = 0; k < 8; ++k) {
        int rr = r0 + k;
        #pragma unroll
        for (int c = 0; c < 4; ++c)
            chh[k][c] = (gx0 + c < 1023) ? chb[(size_t)rr * 1023 + gx0 + c] : 0.f;
        chl0[k] = (gx0 > 0) ? chb[(size_t)rr * 1023 + gx0 - 1] : 0.f;
    }
    int sidx = b * 128 * 128 + rb * 128 + (gx0 >> 3);
    float sval = source[sidx];
    bool  adj  = (mask[sidx] >= 0.5f);

    const unsigned int* tagT = tags + ((((rb > 0   ? s - 1 : s) * 4) + w) << 4);
    const unsigned int* tagB = tags + ((((rb < 127 ? s + 1 : s) * 4) + w) << 4);

    for (int it = 0; it < niter; ++it) {
        const int p = it & 1;          // slot holding S_it edges
        const int q = p ^ 1;           // slot for S_{it+1}

        // wave-boundary cols of S_it -> LDS (double-buffered, 1 barrier)
        if (l == 63 && w < 3) {
            #pragma unroll
            for (int r = 0; r < 8; ++r) sE[p][w][0][r] = o[r][3];
        }
        if (l == 0 && w > 0) {
            #pragma unroll
            for (int r = 0; r < 8; ++r) sE[p][w - 1][1][r] = o[r][0];
        }
        __syncthreads();

        // wave-edge lf/rt for all rows (shfl within wave, LDS across waves)
        float lfS[8], rtS[8];
        int wl = (w > 0) ? w - 1 : 0;
        int wr = (w < 3) ? w : 0;
        #pragma unroll
        for (int r = 0; r < 8; ++r) {
            float a  = __shfl(o[r][3], l - 1);
            float bq = __shfl(o[r][0], l + 1);
            lfS[r] = (l == 0)  ? ((w > 0) ? sE[p][wl][0][r] : 0.f) : a;
            rtS[r] = (l == 63) ? ((w < 3) ? sE[p][wr][1][r] : 0.f) : bq;
        }

        // interior rows 1..6 BEFORE the poll (hidden under neighbor wait)
        float n[8][4];
        float cs = 0.f;
        #pragma unroll
        for (int r = 1; r < 7; ++r) {
            #pragma unroll
            for (int c = 0; c < 4; ++c) {
                float cen = o[r][c];
                float up = o[r - 1][c];
                float dn = o[r + 1][c];
                float lf = (c == 0) ? lfS[r] : o[r][c - 1];
                float rt = (c == 3) ? rtS[r] : o[r][c + 1];
                float cl = (c == 0) ? chl0[r] : chh[r][c - 1];
                float v = cen + 0.24f * ( cvv[r + 1][c] * (dn - cen)
                                        - cvv[r][c]     * (cen - up)
                                        + chh[r][c]     * (rt - cen)
                                        - cl            * (cen - lf) );
                n[r][c] = v; cs += v;
            }
        }

        // poll my 2 row-neighbor tags (lanes 0,1 of this wave; wave-local)
        {
            unsigned int target = (unsigned int)(it + 1);
            bool active = (l == 0) ? (rb > 0) : ((l == 1) ? (rb < 127) : false);
            if (active) {
                const unsigned int* pp = (l == 0) ? tagT : tagB;
                int guard = 0;
                while (__hip_atomic_load(pp, __ATOMIC_RELAXED,
                                         __HIP_MEMORY_SCOPE_AGENT) < target) {
                    if (++guard > (1 << 18)) break;   // bounded: no hard hang
                    __builtin_amdgcn_s_sleep(1);
                }
            }
        }
        asm volatile("" ::: "memory");   // halo loads stay below the poll

        // row halos from slot p (swizzled, lane-consecutive -> coalesced)
        float ht[4] = {0.f, 0.f, 0.f, 0.f}, hb[4] = {0.f, 0.f, 0.f, 0.f};
        if (rb > 0) {
            const float* srcp = rowbuf + (((size_t)p * 256 + (s - 1)) * 2 + 1) * 1024 + swz;
            #pragma unroll
            for (int c = 0; c < 4; ++c) ht[c] = aload(srcp + (c << 6));
        }
        if (rb < 127) {
            const float* srcp = rowbuf + (((size_t)p * 256 + (s + 1)) * 2 + 0) * 1024 + swz;
            #pragma unroll
            for (int c = 0; c < 4; ++c) hb[c] = aload(srcp + (c << 6));
        }

        // edge rows 0 and 7
        #pragma unroll
        for (int c = 0; c < 4; ++c) {
            float cen = o[0][c];
            float up = ht[c], dn = o[1][c];
            float lf = (c == 0) ? lfS[0] : o[0][c - 1];
            float rt = (c == 3) ? rtS[0] : o[0][c + 1];
            float cl = (c == 0) ? chl0[0] : chh[0][c - 1];
            float v = cen + 0.24f * ( cvv[1][c] * (dn - cen) - cvv[0][c] * (cen - up)
                                    + chh[0][c] * (rt - cen) - cl * (cen - lf) );
            n[0][c] = v; cs += v;
        }
        #pragma unroll
        for (int c = 0; c < 4; ++c) {
            float cen = o[7][c];
            float up = o[6][c], dn = hb[c];
            float lf = (c == 0) ? lfS[7] : o[7][c - 1];
            float rt = (c == 3) ? rtS[7] : o[7][c + 1];
            float cl = (c == 0) ? chl0[7] : chh[7][c - 1];
            float v = cen + 0.24f * ( cvv[8][c] * (dn - cen) - cvv[7][c] * (cen - up)
                                    + chh[7][c] * (rt - cen) - cl * (cen - lf) );
            n[7][c] = v; cs += v;
        }

        // adjust: tile mean over 8x8 = this thread's 32 px + xor-partner's
        cs += __shfl_xor(cs, 1);
        float mean  = cs * (1.0f / 64.0f);
        float ratio = adj ? sval / (mean + 1e-8f) : 1.0f;
        #pragma unroll
        for (int r = 0; r < 8; ++r)
            #pragma unroll
            for (int c = 0; c < 4; ++c) o[r][c] = n[r][c] * ratio;

        // publish S_{it+1} edges into slot q (swizzled, coalesced atomics)
        {
            float* dT = rowbuf + (((size_t)q * 256 + s) * 2 + 0) * 1024 + swz;
            float* dB = rowbuf + (((size_t)q * 256 + s) * 2 + 1) * 1024 + swz;
            #pragma unroll
            for (int c = 0; c < 4; ++c) { astore(dT + (c << 6), o[0][c]);
                                          astore(dB + (c << 6), o[7][c]); }
        }
        asm volatile("s_waitcnt vmcnt(0)" ::: "memory");
        if (l == 0)
            __hip_atomic_store(mytag, (unsigned int)(it + 2),
                               __ATOMIC_RELAXED, __HIP_MEMORY_SCOPE_AGENT);
    }

    // final field back to global
    #pragma unroll
    for (int r = 0; r < 8; ++r) {
        float4 v;
        v.x = o[r][0]; v.y = o[r][1]; v.z = o[r][2]; v.w = o[r][3];
        *(float4*)(gdep + (size_t)(r0 + r) * WW + gx0) = v;
    }
}

// ---------------------------------------------------------------------------
extern "C" void kernel_launch(void* const* d_in, const int* in_sizes, int n_in,
                              void* d_out, int out_size, void* d_ws, size_t ws_size,
                              hipStream_t stream)
{
    (void)in_sizes; (void)n_in; (void)out_size; (void)ws_size;
    const float* guide  = (const float*)d_in[0];
    const float* source = (const float*)d_in[1];
    const float* mask   = (const float*)d_in[2];
    const float* ybic   = (const float*)d_in[3];

    float* out   = (float*)d_out;
    float* ypred = out;                       // 2*1024*1024
    float* cv    = out + 2097152;             // 2*1023*1024
    float* ch    = out + 2097152 + 2095104;   // 2*1024*1023

    // Workspace union layout:
    //   [0, 1048576)        : rowbuf (persistent)  OR  dbuf lower half
    //   [1048576, 1081344)  : itags+ftags (persistent) OR dbuf middle
    //   [0, 2097152)        : dbuf (fallback; write-before-read each iter)
    //   [2097152, ...)      : cvmA, chmA, unifA
    float* wsf    = (float*)d_ws;
    float* dbuf   = wsf;
    float* rowbuf = wsf;                             // 2*256*2*1024 = 1048576
    unsigned int* itags = (unsigned int*)(wsf + 1048576);   // 16384 uints
    unsigned int* ftags = itags + 16384;                    // 16384 uints
    float* cvmA   = wsf + 2097152;
    float* chmA   = cvmA + 2 * NBLK * NBLK;
    float* unifA  = chmA + 2 * NBLK * NBLK;

    // Host-side gates (pure queries, graph-capture safe). Cached once.
    static int persist_ok = -1;
    static int fft_ok = -1;
    static int fgs[16], nfg = 0;
    if (persist_ok < 0) {
        int dev = 0;
        (void)hipGetDevice(&dev);
        hipDeviceProp_t prop;
        int nCU = 0;
        if (hipGetDeviceProperties(&prop, dev) == hipSuccess)
            nCU = prop.multiProcessorCount;
        int nb = 0;
        hipError_t e = hipOccupancyMaxActiveBlocksPerMultiprocessor(
            &nb, iter500_strip, 256, 0);
        persist_ok = (e == hipSuccess && nCU > 0 && nb * nCU >= 256) ? 1 : 0;

        int nb2 = 0;
        hipError_t e2 = hipOccupancyMaxActiveBlocksPerMultiprocessor(
            &nb2, fftblk_group, 256, 0);
        fft_ok = 0;
        if (e2 == hipSuccess && nCU > 0) {
            int capb = (nb2 * nCU) / 2 - 16;   // per-batch cap, safety margin
            if (capb >= 64) {
                nfg = 0;
                int start = 0, cnt = 0;
                bool ok = true;
                for (int d = 0; d < 64; ++d) {
                    int lo = (d > 21) ? ((d - 20) >> 1) : 0;
                    int hi = ((d >> 1) < 21) ? (d >> 1) : 21;
                    int wd = hi - lo + 1;
                    if (cnt + wd > capb) {
                        if (nfg >= 15) { ok = false; break; }
                        fgs[nfg * 2] = start; fgs[nfg * 2 + 1] = cnt;
                        ++nfg; start += cnt; cnt = 0;
                    }
                    cnt += wd;
                }
                if (ok && cnt > 0) { fgs[nfg * 2] = start; fgs[nfg * 2 + 1] = cnt; ++nfg; }
                fft_ok = ok ? 1 : 0;
            }
        }
    }

    // 1. edge-stopping coefficients (also outputs 1,2)
    coeff_kernel<<<dim3(4, HH, 2), 256, 0, stream>>>(guide, ybic, cv, ch);
    // 2. per-block stats
    stats_kernel<<<dim3(NBLK, NBLK, 2), 256, 0, stream>>>(cv, ch, cvmA, chmA, unifA);
    // 3. depth <- y_bicubic
    hipMemcpyAsync(ypred, ybic, (size_t)2 * HW * sizeof(float),
                   hipMemcpyDeviceToDevice, stream);
    // 4. tags zeroed each replay (captured -> re-runs per replay).
    hipMemsetAsync(itags, 0, 2 * 16384 * sizeof(unsigned int), stream);

    // 5. blockwise FFT-equivalent diffusion
    if (fft_ok) {
        for (int g = 0; g < nfg; ++g)
            fftblk_group<<<dim3(fgs[g * 2 + 1], 2), 256, 0, stream>>>(
                ypred, cvmA, chmA, unifA, ftags, fgs[g * 2]);
    } else {
        for (int d = 0; d <= 3 * (NBLK - 1); ++d) {
            int lo = (d > NBLK - 1) ? (d - NBLK + 2) / 2 : 0;
            int hi = (d / 2 < NBLK - 1) ? d / 2 : NBLK - 1;
            if (lo > hi) continue;
            fftblk_kernel<<<dim3(hi - lo + 1, 2), 256, 0, stream>>>(
                ypred, cvmA, chmA, unifA, d, lo);
        }
    }

    // 6. 500 diffuse+adjust iterations
    if (persist_ok) {
        iter500_strip<<<dim3(256), 256, 0, stream>>>(
            ypred, cv, ch, source, mask, rowbuf, itags, 500);
    } else {
        for (int i = 0; i < 500; ++i) {
            const float* src = (i & 1) ? dbuf : ypred;
            float*       dst = (i & 1) ? ypred : dbuf;
            iter_kernel<<<dim3(1024), 256, 0, stream>>>(
                src, dst, cv, ch, source, mask);
        }
        // 500 is even: final result lands back in ypred (d_out).
    }
}

// Round 10
// 2068.185 us; speedup vs baseline: 1.2629x; 1.2629x over previous
//
#include <hip/hip_runtime.h>

#define HH 1024
#define WW 1024
#define HW 1048576   // 1024*1024
#define NBLK 22      // fft blocks per dim: range(0,1024,48)

// ---------------------------------------------------------------------------
// Agent-scope RELAXED dword access — the ONLY cross-block primitives used.
// Proven R3/R4/R8: cross-XCD coherent via MALL, no cache-maintenance storm.
// R6/R7 lesson: hand-rolled sc-bit wide stores are NOT visible to these
// readers. Coalescing comes from ADDRESSING (lane-consecutive dwords).
// ---------------------------------------------------------------------------
__device__ __forceinline__ float aload(const float* p)
{
    return __uint_as_float(__hip_atomic_load((const unsigned int*)p,
                           __ATOMIC_RELAXED, __HIP_MEMORY_SCOPE_AGENT));
}
__device__ __forceinline__ void astore(float* p, float v)
{
    __hip_atomic_store((unsigned int*)p, __float_as_uint(v),
                       __ATOMIC_RELAXED, __HIP_MEMORY_SCOPE_AGENT);
}

// ---------------------------------------------------------------------------
// Kernel 1: cv, ch edge-stopping coefficients (also final outputs 1,2)
// ---------------------------------------------------------------------------
__global__ __launch_bounds__(256) void coeff_kernel(
    const float* __restrict__ guide, const float* __restrict__ img,
    float* __restrict__ cv, float* __restrict__ ch)
{
    int x = blockIdx.x * 256 + threadIdx.x;
    int y = blockIdx.y;
    int b = blockIdx.z;
    const float* g0 = guide + (size_t)b * 3 * HW;
    const float* im = img + (size_t)b * HW;
    int p = y * WW + x;
    float f0 = g0[p], f1 = g0[HW + p], f2 = g0[2 * HW + p], f3 = im[p];
    const float KK = 0.03f * 0.03f;
    if (y < HH - 1) {
        int q = p + WW;
        float s = fabsf(g0[q] - f0) + fabsf(g0[HW + q] - f1)
                + fabsf(g0[2 * HW + q] - f2) + fabsf(im[q] - f3);
        float t = s * 0.25f;
        cv[(size_t)b * 1023 * 1024 + p] = 1.0f / (1.0f + t * t / KK);
    }
    if (x < WW - 1) {
        int q = p + 1;
        float s = fabsf(g0[q] - f0) + fabsf(g0[HW + q] - f1)
                + fabsf(g0[2 * HW + q] - f2) + fabsf(im[q] - f3);
        float t = s * 0.25f;
        ch[(size_t)b * 1024 * 1023 + y * 1023 + x] = 1.0f / (1.0f + t * t / KK);
    }
}

__device__ __forceinline__ float block_reduce(float v, float* tmp)
{
    #pragma unroll
    for (int off = 32; off > 0; off >>= 1) v += __shfl_down(v, off);
    __syncthreads();
    if ((threadIdx.x & 63) == 0) tmp[threadIdx.x >> 6] = v;
    __syncthreads();
    return tmp[0] + tmp[1] + tmp[2] + tmp[3];
}

// ---------------------------------------------------------------------------
// Kernel 2: per-(block,batch) stats: cv mean, ch mean, uniform fraction
// ---------------------------------------------------------------------------
__global__ __launch_bounds__(256) void stats_kernel(
    const float* __restrict__ cv, const float* __restrict__ ch,
    float* __restrict__ cvmA, float* __restrict__ chmA, float* __restrict__ unifA)
{
    int iy = blockIdx.x, ix = blockIdx.y, b = blockIdx.z;
    int y0 = iy * 48, x0 = ix * 48;
    int ye = min(y0 + 64, HH), xe = min(x0 + 64, WW);
    int bh = ye - y0, bw = xe - x0;
    const float* cvb = cv + (size_t)b * 1023 * 1024;
    const float* chb = ch + (size_t)b * 1024 * 1023;
    int tid = threadIdx.x;

    int cnt_cv = (bh - 1) * bw;
    float s_cv = 0.f;
    for (int k = tid; k < cnt_cv; k += 256) {
        int r = k / bw, c = k - r * bw;
        s_cv += cvb[(y0 + r) * 1024 + x0 + c];
    }
    int cnt_ch = bh * (bw - 1);
    float s_ch = 0.f;
    for (int k = tid; k < cnt_ch; k += 256) {
        int r = k / (bw - 1), c = k - r * (bw - 1);
        s_ch += chb[(y0 + r) * 1023 + x0 + c];
    }
    int uh = min(ye, 1023) - y0, uw = min(xe, 1023) - x0;
    int cnt_u = uh * uw;
    float s_u = 0.f;
    for (int k = tid; k < cnt_u; k += 256) {
        int r = k / uw, c = k - r * uw;
        int py = y0 + r, px = x0 + c;
        float a1 = 0.f, a2 = 0.f;
        #pragma unroll
        for (int dy = -1; dy <= 1; ++dy)
            #pragma unroll
            for (int dx = -1; dx <= 1; ++dx) {
                int yy = py + dy, xx = px + dx;
                if (yy >= 0 && yy < 1023 && xx >= 0 && xx < 1024) {
                    float v = cvb[yy * 1024 + xx]; a1 += v; a2 += v * v;
                }
            }
        float va = a2 * (1.f / 9.f) - (a1 * (1.f / 9.f)) * (a1 * (1.f / 9.f));
        float b1 = 0.f, b2 = 0.f;
        #pragma unroll
        for (int dy = -1; dy <= 1; ++dy)
            #pragma unroll
            for (int dx = -1; dx <= 1; ++dx) {
                int yy = py + dy, xx = px + dx;
                if (yy >= 0 && yy < 1024 && xx >= 0 && xx < 1023) {
                    float v = chb[yy * 1023 + xx]; b1 += v; b2 += v * v;
                }
            }
        float vb = b2 * (1.f / 9.f) - (b1 * (1.f / 9.f)) * (b1 * (1.f / 9.f));
        s_u += (va < 0.1f && vb < 0.1f) ? 1.f : 0.f;
    }

    __shared__ float tmp[4];
    float t_cv = block_reduce(s_cv, tmp);
    float t_ch = block_reduce(s_ch, tmp);
    float t_u  = block_reduce(s_u, tmp);
    if (tid == 0) {
        int bi = (b * NBLK + iy) * NBLK + ix;
        cvmA[bi]  = t_cv / (float)cnt_cv;
        chmA[bi]  = t_ch / (float)cnt_ch;
        unifA[bi] = t_u / (float)cnt_u;
    }
}

// ---------------------------------------------------------------------------
// Kernel 3a (fallback): one diagonal per launch, plain L2 path.
// ---------------------------------------------------------------------------
__global__ __launch_bounds__(256) void fftblk_kernel(
    float* __restrict__ depth,
    const float* __restrict__ cvmA, const float* __restrict__ chmA,
    const float* __restrict__ unifA, int d, int iy_lo)
{
    int iy = iy_lo + (int)blockIdx.x;
    int ix = d - 2 * iy;
    int b = blockIdx.y;
    int bi = (b * NBLK + iy) * NBLK + ix;
    if (!(unifA[bi] > 0.7f)) return;

    int y0 = iy * 48, x0 = ix * 48;
    int bh = min(64, HH - y0), bw = min(64, WW - x0);
    int npix = bh * bw;
    int bwm = bw - 1, bhm = bh - 1;
    int lw = (bw == 64) ? 6 : 4;
    float av = 0.24f * cvmA[bi];
    float ah = 0.24f * chmA[bi];

    __shared__ float bufA[4096], bufB[4096], bufO[4096];
    float* cur = bufA;
    float* nxt = bufB;
    int tid = threadIdx.x;
    float* gbase = depth + (size_t)b * HW + y0 * WW + x0;

    for (int idx = tid; idx < npix; idx += 256) {
        int i = idx >> lw, j = idx & bwm;
        float v = gbase[i * WW + j];
        cur[idx] = v; bufO[idx] = v;
    }
    __syncthreads();

    for (int it = 0; it < 10; ++it) {
        for (int idx = tid; idx < npix; idx += 256) {
            int i = idx >> lw, j = idx & bwm;
            float c  = cur[idx];
            float up = cur[(((i - 1) & bhm) << lw) | j];
            float dn = cur[(((i + 1) & bhm) << lw) | j];
            float lf = cur[(i << lw) | ((j - 1) & bwm)];
            float rt = cur[(i << lw) | ((j + 1) & bwm)];
            nxt[idx] = c + av * (up + dn - 2.f * c) + ah * (lf + rt - 2.f * c);
        }
        __syncthreads();
        float* t = cur; cur = nxt; nxt = t;
    }

    const float inv16 = 1.f / 16.f;
    for (int idx = tid; idx < npix; idx += 256) {
        int i = idx >> lw, j = idx & bwm;
        float wy = (y0 > 0 && i < 16) ? (float)i * inv16 : 1.f;
        float wx = (x0 > 0 && j < 16) ? (float)j * inv16 : 1.f;
        float w = wy * wx;
        gbase[i * WW + j] = bufO[idx] * (1.f - w) + cur[idx] * w;
    }
}

// ---------------------------------------------------------------------------
// Kernel 3b: GROUPED fftblk, REGISTER-TILED Jacobi.
// R10 fix: LDS edge arrays padded to inner dim 65. R9's [..][64] layout put
// consecutive tx at stride 64 dwords = 0 mod 32 banks -> 16-way conflicts
// on every column-edge access (SQ_LDS_BANK_CONFLICT 3.7e7, 1472us). With 65
// (stride = 1 mod 32), all four arrays' write AND read patterns are
// conflict-free. LDS 32.5KB -> still >=4 blocks/CU, single group launch.
// ---------------------------------------------------------------------------
__global__ __launch_bounds__(256) void fftblk_group(
    float* __restrict__ depth,
    const float* __restrict__ cvmA, const float* __restrict__ chmA,
    const float* __restrict__ unifA, unsigned int* __restrict__ ftags,
    int base)
{
    // decode diagonal-major index -> (iy, ix)
    int rem = base + (int)blockIdx.x;
    int iy = 0, ix = 0;
    for (int d = 0; d < 64; ++d) {
        int lo = (d > 21) ? ((d - 20) >> 1) : 0;
        int hi = ((d >> 1) < 21) ? (d >> 1) : 21;
        int wd = hi - lo + 1;
        if (rem < wd) { iy = lo + rem; ix = d - 2 * iy; break; }
        rem -= wd;
    }
    int b = blockIdx.y;
    int bi = (b * NBLK + iy) * NBLK + ix;
    int tid = threadIdx.x;

    // wait for predecessors (tags, lanes 0..3 of wave 0)
    {
        bool act = false; int di = 0, dj = 0;
        if (tid == 0) { act = (ix > 0);            di = iy;     dj = ix - 1; }
        if (tid == 1) { act = (iy > 0 && ix > 0);  di = iy - 1; dj = ix - 1; }
        if (tid == 2) { act = (iy > 0);            di = iy - 1; dj = ix;     }
        if (tid == 3) { act = (iy > 0 && ix < 21); di = iy - 1; dj = ix + 1; }
        if (tid < 4 && act) {
            const unsigned int* tp = ftags + (((b * NBLK + di) * NBLK + dj) << 4);
            int guard = 0;
            while (__hip_atomic_load(tp, __ATOMIC_RELAXED,
                                     __HIP_MEMORY_SCOPE_AGENT) < 1u) {
                if (++guard > (1 << 20)) break;
                __builtin_amdgcn_s_sleep(2);
            }
        }
    }
    __syncthreads();

    bool active = (unifA[bi] > 0.7f);
    if (active) {
        int y0 = iy * 48, x0 = ix * 48;
        int bh = min(64, HH - y0), bw = min(64, WW - x0);
        const int RH = bh >> 4;   // 4 or 1
        const int RW = bw >> 4;   // 4 or 1
        float av = 0.24f * cvmA[bi];
        float ah = 0.24f * chmA[bi];

        // edge-exchange LDS, parity-double-buffered; inner dim PADDED to 65
        // (bank stride 1 mod 32 -> conflict-free for row AND column access).
        __shared__ float rT[2][16][65];   // each thread-row's TOP cells
        __shared__ float rB[2][16][65];   // each thread-row's BOTTOM cells
        __shared__ float cL[2][16][65];   // each thread-col's LEFT cells
        __shared__ float cR[2][16][65];   // each thread-col's RIGHT cells

        const int ty = tid >> 4, tx = tid & 15;
        float* gbase = depth + (size_t)b * HW + y0 * WW + x0;

        // tile into registers (orig kept for the blend)
        float cur[4][4], orig[4][4];
        #pragma unroll
        for (int r = 0; r < 4; ++r)
            #pragma unroll
            for (int c = 0; c < 4; ++c)
                if (r < RH && c < RW) {
                    float v = aload(gbase + (RH * ty + r) * WW + RW * tx + c);
                    cur[r][c] = v; orig[r][c] = v;
                }

        for (int it = 0; it < 10; ++it) {
            const int p = it & 1;
            // publish tile edges (static register indices via RH/RW branch)
            #pragma unroll
            for (int c = 0; c < 4; ++c)
                if (c < RW) {
                    rT[p][ty][RW * tx + c] = cur[0][c];
                    rB[p][ty][RW * tx + c] = (RH == 4) ? cur[3][c] : cur[0][c];
                }
            #pragma unroll
            for (int r = 0; r < 4; ++r)
                if (r < RH) {
                    cL[p][tx][RH * ty + r] = cur[r][0];
                    cR[p][tx][RH * ty + r] = (RW == 4) ? cur[r][3] : cur[r][0];
                }
            __syncthreads();

            // 5-point periodic Jacobi step, interior in registers
            float nxt[4][4];
            #pragma unroll
            for (int r = 0; r < 4; ++r)
                #pragma unroll
                for (int c = 0; c < 4; ++c)
                    if (r < RH && c < RW) {
                        float ce = cur[r][c];
                        float up = (r > 0) ? cur[r - 1][c]
                                           : rB[p][(ty - 1) & 15][RW * tx + c];
                        float dn = rT[p][(ty + 1) & 15][RW * tx + c];
                        if (r + 1 < 4) { if (r + 1 < RH) dn = cur[r + 1][c]; }
                        float lf = (c > 0) ? cur[r][c - 1]
                                           : cR[p][(tx - 1) & 15][RH * ty + r];
                        float rt = cL[p][(tx + 1) & 15][RH * ty + r];
                        if (c + 1 < 4) { if (c + 1 < RW) rt = cur[r][c + 1]; }
                        nxt[r][c] = ce + av * (up + dn - 2.f * ce)
                                       + ah * (lf + rt - 2.f * ce);
                    }
            #pragma unroll
            for (int r = 0; r < 4; ++r)
                #pragma unroll
                for (int c = 0; c < 4; ++c)
                    if (r < RH && c < RW) cur[r][c] = nxt[r][c];
            // no trailing barrier: next step writes parity p^1; the single
            // barrier above orders write(p^1) against all reads of (p^1).
        }

        // blend with original and write back (coalesced agent-scope)
        const float inv16 = 1.f / 16.f;
        #pragma unroll
        for (int r = 0; r < 4; ++r)
            #pragma unroll
            for (int c = 0; c < 4; ++c)
                if (r < RH && c < RW) {
                    int i = RH * ty + r, j = RW * tx + c;
                    float wy = (y0 > 0 && i < 16) ? (float)i * inv16 : 1.f;
                    float wx = (x0 > 0 && j < 16) ? (float)j * inv16 : 1.f;
                    float w = wy * wx;
                    astore(gbase + i * WW + j,
                           orig[r][c] * (1.f - w) + cur[r][c] * w);
                }
        asm volatile("s_waitcnt vmcnt(0)" ::: "memory");
    }
    __syncthreads();   // all waves drained before tag raise
    if (tid == 0)
        __hip_atomic_store(ftags + (bi << 4), 1u, __ATOMIC_RELAXED,
                           __HIP_MEMORY_SCOPE_AGENT);
}

// ---------------------------------------------------------------------------
// Kernel 4a (fallback, known-good): one scan iteration per launch.
// ---------------------------------------------------------------------------
__global__ __launch_bounds__(256, 4) void iter_kernel(
    const float* __restrict__ Iin, float* __restrict__ Iout,
    const float* __restrict__ cv, const float* __restrict__ ch,
    const float* __restrict__ source, const float* __restrict__ mask)
{
    const int w = blockIdx.x;
    const int xcd = w & 7, j = w >> 3;
    const int grb = xcd * 32 + (j >> 2);
    const int b  = grb >> 7;
    const int r0 = (grb & 127) * 8;
    const int c0 = (j & 3) * 256;
    const int tid = threadIdx.x;
    __shared__ float sI[10][258];
    const float* Ib  = Iin + (size_t)b * HW;
    const float* cvb = cv + (size_t)b * 1023 * 1024;
    const float* chb = ch + (size_t)b * 1024 * 1023;

    for (int k = tid; k < 10 * 258; k += 256) {
        int r = k / 258, c = k - r * 258;
        int gy = r0 - 1 + r, gx = c0 - 1 + c;
        float v = 0.f;
        if (gy >= 0 && gy < HH && gx >= 0 && gx < WW) v = Ib[gy * WW + gx];
        sI[r][c] = v;
    }

    const int gx = c0 + tid;
    float cvv[9];
    #pragma unroll
    for (int k = 0; k < 9; ++k) {
        int gr = r0 - 1 + k;
        cvv[k] = (gr >= 0 && gr < 1023) ? cvb[gr * 1024 + gx] : 0.f;
    }
    float chl[8], chh[8];
    #pragma unroll
    for (int k = 0; k < 8; ++k) {
        int rr = r0 + k;
        chh[k] = (gx < 1023) ? chb[rr * 1023 + gx] : 0.f;
        chl[k] = (gx > 0)    ? chb[rr * 1023 + gx - 1] : 0.f;
    }
    __syncthreads();

    float o[8];
    #pragma unroll
    for (int r = 0; r < 8; ++r) {
        float c  = sI[r + 1][tid + 1];
        float up = sI[r][tid + 1], dn = sI[r + 2][tid + 1];
        float lf = sI[r + 1][tid], rt = sI[r + 1][tid + 2];
        o[r] = c + 0.24f * ( cvv[r + 1] * (dn - c) - cvv[r] * (c - up)
                           + chh[r] * (rt - c)     - chl[r] * (c - lf) );
    }

    float colsum = 0.f;
    #pragma unroll
    for (int r = 0; r < 8; ++r) colsum += o[r];
    colsum += __shfl_xor(colsum, 1);
    colsum += __shfl_xor(colsum, 2);
    colsum += __shfl_xor(colsum, 4);
    float mean = colsum * (1.0f / 64.0f);

    int sy = r0 >> 3;
    int sx = (c0 >> 3) + (tid >> 3);
    int sidx = b * 128 * 128 + sy * 128 + sx;
    float ratio = (mask[sidx] < 0.5f) ? 1.0f : source[sidx] / (mean + 1e-8f);

    float* Ob = Iout + (size_t)b * HW;
    #pragma unroll
    for (int r = 0; r < 8; ++r)
        Ob[(r0 + r) * WW + c0 + tid] = o[r] * ratio;
}

// ---------------------------------------------------------------------------
// Kernel 4b: ALL 500 iterations, strip-persistent (R8, proven: 1086us,
// WRITE_SIZE == logical). Unchanged.
// ---------------------------------------------------------------------------
__global__ __launch_bounds__(256, 1) void iter500_strip(
    float* __restrict__ depth,
    const float* __restrict__ cv, const float* __restrict__ ch,
    const float* __restrict__ source, const float* __restrict__ mask,
    float* __restrict__ rowbuf,        // [slot2][strip256][which2][w4][c4][l64]
    unsigned int* __restrict__ tags,   // [strip256][wave4] stride-16 uints
    int niter)
{
    const int s   = blockIdx.x;        // strip 0..255
    const int b   = s >> 7;
    const int rb  = s & 127;
    const int r0  = rb * 8;
    const int tid = threadIdx.x;
    const int w   = tid >> 6;          // wave 0..3 (col segment)
    const int l   = tid & 63;
    const int gx0 = (w << 8) + (l << 2);   // first of 4 owned columns
    const int swz = (w << 8) + l;          // swizzled base: + (c<<6) per col

    __shared__ float sE[2][3][2][8];   // [slot][boundary][left/right][row]

    float* gdep = depth + (size_t)b * HW;

    // ---- field into registers (float4 rows), publish(0) ASAP ----
    float o[8][4];
    #pragma unroll
    for (int r = 0; r < 8; ++r) {
        float4 v = *(const float4*)(gdep + (size_t)(r0 + r) * WW + gx0);
        o[r][0] = v.x; o[r][1] = v.y; o[r][2] = v.z; o[r][3] = v.w;
    }
    unsigned int* mytag = tags + ((s * 4 + w) << 4);
    {
        float* dT = rowbuf + ((size_t)s * 2 + 0) * 1024 + swz;   // slot 0
        float* dB = rowbuf + ((size_t)s * 2 + 1) * 1024 + swz;
        #pragma unroll
        for (int c = 0; c < 4; ++c) { astore(dT + (c << 6), o[0][c]);
                                      astore(dB + (c << 6), o[7][c]); }
        asm volatile("s_waitcnt vmcnt(0)" ::: "memory");
        if (l == 0)
            __hip_atomic_store(mytag, 1u, __ATOMIC_RELAXED, __HIP_MEMORY_SCOPE_AGENT);
    }

    // ---- loop-invariant coefficients into registers ----
    const float* cvb = cv + (size_t)b * 1023 * 1024;
    const float* chb = ch + (size_t)b * 1024 * 1023;
    float cvv[9][4];
    #pragma unroll
    for (int k = 0; k < 9; ++k) {
        int gr = r0 - 1 + k;
        #pragma unroll
        for (int c = 0; c < 4; ++c)
            cvv[k][c] = (gr >= 0 && gr < 1023) ? cvb[(size_t)gr * 1024 + gx0 + c] : 0.f;
    }
    float chh[8][4], chl0[8];
    #pragma unroll
    for (int k = 0; k < 8; ++k) {
        int rr = r0 + k;
        #pragma unroll
        for (int c = 0; c < 4; ++c)
            chh[k][c] = (gx0 + c < 1023) ? chb[(size_t)rr * 1023 + gx0 + c] : 0.f;
        chl0[k] = (gx0 > 0) ? chb[(size_t)rr * 1023 + gx0 - 1] : 0.f;
    }
    int sidx = b * 128 * 128 + rb * 128 + (gx0 >> 3);
    float sval = source[sidx];
    bool  adj  = (mask[sidx] >= 0.5f);

    const unsigned int* tagT = tags + ((((rb > 0   ? s - 1 : s) * 4) + w) << 4);
    const unsigned int* tagB = tags + ((((rb < 127 ? s + 1 : s) * 4) + w) << 4);

    for (int it = 0; it < niter; ++it) {
        const int p = it & 1;          // slot holding S_it edges
        const int q = p ^ 1;           // slot for S_{it+1}

        // wave-boundary cols of S_it -> LDS (double-buffered, 1 barrier)
        if (l == 63 && w < 3) {
            #pragma unroll
            for (int r = 0; r < 8; ++r) sE[p][w][0][r] = o[r][3];
        }
        if (l == 0 && w > 0) {
            #pragma unroll
            for (int r = 0; r < 8; ++r) sE[p][w - 1][1][r] = o[r][0];
        }
        __syncthreads();

        // wave-edge lf/rt for all rows (shfl within wave, LDS across waves)
        float lfS[8], rtS[8];
        int wl = (w > 0) ? w - 1 : 0;
        int wr = (w < 3) ? w : 0;
        #pragma unroll
        for (int r = 0; r < 8; ++r) {
            float a  = __shfl(o[r][3], l - 1);
            float bq = __shfl(o[r][0], l + 1);
            lfS[r] = (l == 0)  ? ((w > 0) ? sE[p][wl][0][r] : 0.f) : a;
            rtS[r] = (l == 63) ? ((w < 3) ? sE[p][wr][1][r] : 0.f) : bq;
        }

        // interior rows 1..6 BEFORE the poll (hidden under neighbor wait)
        float n[8][4];
        float cs = 0.f;
        #pragma unroll
        for (int r = 1; r < 7; ++r) {
            #pragma unroll
            for (int c = 0; c < 4; ++c) {
                float cen = o[r][c];
                float up = o[r - 1][c];
                float dn = o[r + 1][c];
                float lf = (c == 0) ? lfS[r] : o[r][c - 1];
                float rt = (c == 3) ? rtS[r] : o[r][c + 1];
                float cl = (c == 0) ? chl0[r] : chh[r][c - 1];
                float v = cen + 0.24f * ( cvv[r + 1][c] * (dn - cen)
                                        - cvv[r][c]     * (cen - up)
                                        + chh[r][c]     * (rt - cen)
                                        - cl            * (cen - lf) );
                n[r][c] = v; cs += v;
            }
        }

        // poll my 2 row-neighbor tags (lanes 0,1 of this wave; wave-local)
        {
            unsigned int target = (unsigned int)(it + 1);
            bool active = (l == 0) ? (rb > 0) : ((l == 1) ? (rb < 127) : false);
            if (active) {
                const unsigned int* pp = (l == 0) ? tagT : tagB;
                int guard = 0;
                while (__hip_atomic_load(pp, __ATOMIC_RELAXED,
                                         __HIP_MEMORY_SCOPE_AGENT) < target) {
                    if (++guard > (1 << 18)) break;   // bounded: no hard hang
                    __builtin_amdgcn_s_sleep(1);
                }
            }
        }
        asm volatile("" ::: "memory");   // halo loads stay below the poll

        // row halos from slot p (swizzled, lane-consecutive -> coalesced)
        float ht[4] = {0.f, 0.f, 0.f, 0.f}, hb[4] = {0.f, 0.f, 0.f, 0.f};
        if (rb > 0) {
            const float* srcp = rowbuf + (((size_t)p * 256 + (s - 1)) * 2 + 1) * 1024 + swz;
            #pragma unroll
            for (int c = 0; c < 4; ++c) ht[c] = aload(srcp + (c << 6));
        }
        if (rb < 127) {
            const float* srcp = rowbuf + (((size_t)p * 256 + (s + 1)) * 2 + 0) * 1024 + swz;
            #pragma unroll
            for (int c = 0; c < 4; ++c) hb[c] = aload(srcp + (c << 6));
        }

        // edge rows 0 and 7
        #pragma unroll
        for (int c = 0; c < 4; ++c) {
            float cen = o[0][c];
            float up = ht[c], dn = o[1][c];
            float lf = (c == 0) ? lfS[0] : o[0][c - 1];
            float rt = (c == 3) ? rtS[0] : o[0][c + 1];
            float cl = (c == 0) ? chl0[0] : chh[0][c - 1];
            float v = cen + 0.24f * ( cvv[1][c] * (dn - cen) - cvv[0][c] * (cen - up)
                                    + chh[0][c] * (rt - cen) - cl * (cen - lf) );
            n[0][c] = v; cs += v;
        }
        #pragma unroll
        for (int c = 0; c < 4; ++c) {
            float cen = o[7][c];
            float up = o[6][c], dn = hb[c];
            float lf = (c == 0) ? lfS[7] : o[7][c - 1];
            float rt = (c == 3) ? rtS[7] : o[7][c + 1];
            float cl = (c == 0) ? chl0[7] : chh[7][c - 1];
            float v = cen + 0.24f * ( cvv[8][c] * (dn - cen) - cvv[7][c] * (cen - up)
                                    + chh[7][c] * (rt - cen) - cl * (cen - lf) );
            n[7][c] = v; cs += v;
        }

        // adjust: tile mean over 8x8 = this thread's 32 px + xor-partner's
        cs += __shfl_xor(cs, 1);
        float mean  = cs * (1.0f / 64.0f);
        float ratio = adj ? sval / (mean + 1e-8f) : 1.0f;
        #pragma unroll
        for (int r = 0; r < 8; ++r)
            #pragma unroll
            for (int c = 0; c < 4; ++c) o[r][c] = n[r][c] * ratio;

        // publish S_{it+1} edges into slot q (swizzled, coalesced atomics)
        {
            float* dT = rowbuf + (((size_t)q * 256 + s) * 2 + 0) * 1024 + swz;
            float* dB = rowbuf + (((size_t)q * 256 + s) * 2 + 1) * 1024 + swz;
            #pragma unroll
            for (int c = 0; c < 4; ++c) { astore(dT + (c << 6), o[0][c]);
                                          astore(dB + (c << 6), o[7][c]); }
        }
        asm volatile("s_waitcnt vmcnt(0)" ::: "memory");
        if (l == 0)
            __hip_atomic_store(mytag, (unsigned int)(it + 2),
                               __ATOMIC_RELAXED, __HIP_MEMORY_SCOPE_AGENT);
    }

    // final field back to global
    #pragma unroll
    for (int r = 0; r < 8; ++r) {
        float4 v;
        v.x = o[r][0]; v.y = o[r][1]; v.z = o[r][2]; v.w = o[r][3];
        *(float4*)(gdep + (size_t)(r0 + r) * WW + gx0) = v;
    }
}

// ---------------------------------------------------------------------------
extern "C" void kernel_launch(void* const* d_in, const int* in_sizes, int n_in,
                              void* d_out, int out_size, void* d_ws, size_t ws_size,
                              hipStream_t stream)
{
    (void)in_sizes; (void)n_in; (void)out_size; (void)ws_size;
    const float* guide  = (const float*)d_in[0];
    const float* source = (const float*)d_in[1];
    const float* mask   = (const float*)d_in[2];
    const float* ybic   = (const float*)d_in[3];

    float* out   = (float*)d_out;
    float* ypred = out;                       // 2*1024*1024
    float* cv    = out + 2097152;             // 2*1023*1024
    float* ch    = out + 2097152 + 2095104;   // 2*1024*1023

    // Workspace union layout:
    //   [0, 1048576)        : rowbuf (persistent)  OR  dbuf lower half
    //   [1048576, 1081344)  : itags+ftags (persistent) OR dbuf middle
    //   [0, 2097152)        : dbuf (fallback; write-before-read each iter)
    //   [2097152, ...)      : cvmA, chmA, unifA
    float* wsf    = (float*)d_ws;
    float* dbuf   = wsf;
    float* rowbuf = wsf;                             // 2*256*2*1024 = 1048576
    unsigned int* itags = (unsigned int*)(wsf + 1048576);   // 16384 uints
    unsigned int* ftags = itags + 16384;                    // 16384 uints
    float* cvmA   = wsf + 2097152;
    float* chmA   = cvmA + 2 * NBLK * NBLK;
    float* unifA  = chmA + 2 * NBLK * NBLK;

    // Host-side gates (pure queries, graph-capture safe). Cached once.
    static int persist_ok = -1;
    static int fft_ok = -1;
    static int fgs[16], nfg = 0;
    if (persist_ok < 0) {
        int dev = 0;
        (void)hipGetDevice(&dev);
        hipDeviceProp_t prop;
        int nCU = 0;
        if (hipGetDeviceProperties(&prop, dev) == hipSuccess)
            nCU = prop.multiProcessorCount;
        int nb = 0;
        hipError_t e = hipOccupancyMaxActiveBlocksPerMultiprocessor(
            &nb, iter500_strip, 256, 0);
        persist_ok = (e == hipSuccess && nCU > 0 && nb * nCU >= 256) ? 1 : 0;

        int nb2 = 0;
        hipError_t e2 = hipOccupancyMaxActiveBlocksPerMultiprocessor(
            &nb2, fftblk_group, 256, 0);
        fft_ok = 0;
        if (e2 == hipSuccess && nCU > 0) {
            int capb = (nb2 * nCU) / 2 - 16;   // per-batch cap, safety margin
            if (capb >= 64) {
                nfg = 0;
                int start = 0, cnt = 0;
                bool ok = true;
                for (int d = 0; d < 64; ++d) {
                    int lo = (d > 21) ? ((d - 20) >> 1) : 0;
                    int hi = ((d >> 1) < 21) ? (d >> 1) : 21;
                    int wd = hi - lo + 1;
                    if (cnt + wd > capb) {
                        if (nfg >= 15) { ok = false; break; }
                        fgs[nfg * 2] = start; fgs[nfg * 2 + 1] = cnt;
                        ++nfg; start += cnt; cnt = 0;
                    }
                    cnt += wd;
                }
                if (ok && cnt > 0) { fgs[nfg * 2] = start; fgs[nfg * 2 + 1] = cnt; ++nfg; }
                fft_ok = ok ? 1 : 0;
            }
        }
    }

    // 1. edge-stopping coefficients (also outputs 1,2)
    coeff_kernel<<<dim3(4, HH, 2), 256, 0, stream>>>(guide, ybic, cv, ch);
    // 2. per-block stats
    stats_kernel<<<dim3(NBLK, NBLK, 2), 256, 0, stream>>>(cv, ch, cvmA, chmA, unifA);
    // 3. depth <- y_bicubic
    hipMemcpyAsync(ypred, ybic, (size_t)2 * HW * sizeof(float),
                   hipMemcpyDeviceToDevice, stream);
    // 4. tags zeroed each replay (captured -> re-runs per replay).
    hipMemsetAsync(itags, 0, 2 * 16384 * sizeof(unsigned int), stream);

    // 5. blockwise FFT-equivalent diffusion
    if (fft_ok) {
        for (int g = 0; g < nfg; ++g)
            fftblk_group<<<dim3(fgs[g * 2 + 1], 2), 256, 0, stream>>>(
                ypred, cvmA, chmA, unifA, ftags, fgs[g * 2]);
    } else {
        for (int d = 0; d <= 3 * (NBLK - 1); ++d) {
            int lo = (d > NBLK - 1) ? (d - NBLK + 2) / 2 : 0;
            int hi = (d / 2 < NBLK - 1) ? d / 2 : NBLK - 1;
            if (lo > hi) continue;
            fftblk_kernel<<<dim3(hi - lo + 1, 2), 256, 0, stream>>>(
                ypred, cvmA, chmA, unifA, d, lo);
        }
    }

    // 6. 500 diffuse+adjust iterations
    if (persist_ok) {
        iter500_strip<<<dim3(256), 256, 0, stream>>>(
            ypred, cv, ch, source, mask, rowbuf, itags, 500);
    } else {
        for (int i = 0; i < 500; ++i) {
            const float* src = (i & 1) ? dbuf : ypred;
            float*       dst = (i & 1) ? ypred : dbuf;
            iter_kernel<<<dim3(1024), 256, 0, stream>>>(
                src, dst, cv, ch, source, mask);
        }
        // 500 is even: final result lands back in ypred (d_out).
    }
}